// Round 16
// baseline (77.522 us; speedup 1.0000x reference)
//
#include <hip/hip_runtime.h>

#define GAT_ALPHA 0.2f
#define INV_N (1.0f / 2048.0f)

typedef float f32x4 __attribute__((ext_vector_type(4)));
typedef int   i32x4 __attribute__((ext_vector_type(4)));
typedef __bf16 bf16x8 __attribute__((ext_vector_type(8)));
typedef unsigned short us8 __attribute__((ext_vector_type(8)));

__device__ __forceinline__ unsigned short f2bf(float x) {
  union { float f; unsigned u; } v; v.f = x;
  unsigned r = v.u + 0x7FFFu + ((v.u >> 16) & 1u);   // RNE
  return (unsigned short)(r >> 16);
}
__device__ __forceinline__ float lrelu(float x) {
  return fmaxf(x, 0.f) + GAT_ALPHA * fminf(x, 0.f);
}
__device__ __forceinline__ void lgkm_barrier() {
  asm volatile("s_waitcnt lgkmcnt(0)" ::: "memory");
  __builtin_amdgcn_s_barrier();
  __builtin_amdgcn_sched_barrier(0);
}

// ---------------- k0: Wh = h @ W (f32), s1/s2, WhT in bf16 [b][f][j] ----------------
__global__ __launch_bounds__(256)
void k0_wh(const float* __restrict__ h, const float* __restrict__ W,
           const float* __restrict__ a, unsigned short* __restrict__ WhT,
           float* __restrict__ s1g, float* __restrict__ s2g)
{
  __shared__ float h_s[64][132];
  __shared__ float W_s[128][64];
  __shared__ float wt_s[64][66];
  __shared__ float a_s[128];
  const int t = threadIdx.x;
  const int b = blockIdx.y;
  const int r0 = blockIdx.x * 64;

#pragma unroll
  for (int v = 0; v < 8; ++v) {
    int c = v * 256 + t;
    int k = c >> 4, fo = (c & 15) << 2;
    *(float4*)&W_s[k][fo] = *(const float4*)&W[k * 64 + fo];
  }
#pragma unroll
  for (int v = 0; v < 8; ++v) {
    int c = v * 256 + t;
    int r = c >> 5, ko = (c & 31) << 2;
    *(float4*)&h_s[r][ko] = *(const float4*)&h[((size_t)(b * 2048 + r0 + r)) * 128 + ko];
  }
  if (t < 128) a_s[t] = a[t];
  __syncthreads();

  const int tg = t >> 4;          // 0..15
  const int tf = (t & 15) << 2;   // f base
  float acc[4][4] = {};
#pragma unroll
  for (int k4 = 0; k4 < 32; ++k4) {
    float4 hv[4];
#pragma unroll
    for (int i = 0; i < 4; ++i)
      hv[i] = *(const float4*)&h_s[i * 16 + tg][k4 * 4];
#pragma unroll
    for (int kk = 0; kk < 4; ++kk) {
      float4 wv = *(const float4*)&W_s[k4 * 4 + kk][tf];
#pragma unroll
      for (int i = 0; i < 4; ++i) {
        float hx = ((const float*)&hv[i])[kk];
        acc[i][0] = fmaf(hx, wv.x, acc[i][0]);
        acc[i][1] = fmaf(hx, wv.y, acc[i][1]);
        acc[i][2] = fmaf(hx, wv.z, acc[i][2]);
        acc[i][3] = fmaf(hx, wv.w, acc[i][3]);
      }
    }
  }
#pragma unroll
  for (int i = 0; i < 4; ++i)
#pragma unroll
    for (int j = 0; j < 4; ++j)
      wt_s[tf + j][i * 16 + tg] = acc[i][j];
  __syncthreads();

  if (t < 64) {   // s1/s2 for row r = t (f32 exact)
    float v1 = 0.f, v2 = 0.f;
#pragma unroll 8
    for (int f = 0; f < 64; ++f) {
      float w = wt_s[f][t];
      v1 = fmaf(w, a_s[f], v1);
      v2 = fmaf(w, a_s[64 + f], v2);
    }
    s1g[b * 2048 + r0 + t] = v1;
    s2g[b * 2048 + r0 + t] = v2;
  }
  {  // WhT bf16 write, [b][f][j]
    int f = t >> 2, rb = (t & 3) << 4;
    unsigned short pk[16];
#pragma unroll
    for (int i = 0; i < 16; ++i) pk[i] = f2bf(wt_s[f][rb + i]);
    size_t base = ((size_t)(b * 64 + f)) * 2048 + r0 + rb;
    *(uint4*)&WhT[base]     = *(uint4*)&pk[0];
    *(uint4*)&WhT[base + 8] = *(uint4*)&pk[8];
  }
}

// ---------------- k1y: adj scan -> masks(gm8) + denom(lrow) + UNNORMALIZED Y via MFMA ----
// 16-row strips, 1024 blocks. One pass over j. Per 128-j iter: adj (dbuf'd) ->
// masked e (bf16) -> att_s[p]; wave-private wh_s (R15-proven, no barrier); ONE
// lgkm barrier; 4 MFMA accumulate Y += (M.E) @ Wh^T. Y, sum, masks written out;
// NO att store here. gm8 byte convention: byte j>>3 of row, bit j&7.
__global__ __launch_bounds__(256)
void k1y(const int* __restrict__ adj, const unsigned short* __restrict__ WhT,
         const float* __restrict__ s1g, const float* __restrict__ s2g,
         float* __restrict__ lrow, unsigned char* __restrict__ gm8,
         float* __restrict__ yws)
{
  __shared__ unsigned short att_s[2][16][136];   // 8.7 KB dbuf (masked-e bf16)
  __shared__ unsigned short wh_s[4][16][136];    // 17.4 KB wave-private

  const int t = threadIdx.x;
  const int b = blockIdx.y;
  const int r0 = blockIdx.x * 16;
  const size_t rowb = (size_t)(b * 2048 + r0);
  const int r = t >> 4, q = t & 15;              // scan layout: row r, j-slot q
  const int* __restrict__ arow = adj + (rowb + r) * 2048;
  const float* __restrict__ z = s2g + b * 2048;
  const float s1v = s1g[rowb + r];

  const int w  = t >> 6, l = t & 63;
  const int ln = l & 15, lg = l >> 4;
  const unsigned short* __restrict__ wsrc =
      WhT + ((size_t)(b * 64 + w * 16)) * 2048;

  // initial adj loads (iter 0): thread covers j = q*8 .. q*8+8
  i32x4 aA = *(const i32x4*)&arow[q * 8];
  i32x4 aB = *(const i32x4*)&arow[q * 8 + 4];

  float sum = 0.f;
  f32x4 acc = {0.f, 0.f, 0.f, 0.f};
  int p = 0;

  for (int j0 = 0; j0 < 2048; j0 += 128) {
    // prefetch next iter's adj (stays ahead of this iter's tiny gm8 store)
    i32x4 nA, nB;
    if (j0 < 1920) {
      nA = *(const i32x4*)&arow[j0 + 128 + q * 8];
      nB = *(const i32x4*)&arow[j0 + 128 + q * 8 + 4];
    }
    // wave-private Wh loads (T14 same-iter)
    uint4 wreg[4];
#pragma unroll
    for (int v = 0; v < 4; ++v)
      wreg[v] = *(const uint4*)&wsrc[(size_t)(v * 4 + lg) * 2048 + j0 + ln * 8];

    const float4 z0 = *(const float4*)&z[j0 + q * 8];
    const float4 z1 = *(const float4*)&z[j0 + q * 8 + 4];

    unsigned bits = 0;
    float e[8];
#define PE(m, av, zz)                                      \
    { const bool pm = (av) > 0;                            \
      bits |= (unsigned)pm << (m);                         \
      e[m] = pm ? __expf(lrelu(s1v + (zz))) : 0.f;         \
      sum += e[m]; }
    PE(0, aA.x, z0.x) PE(1, aA.y, z0.y) PE(2, aA.z, z0.z) PE(3, aA.w, z0.w)
    PE(4, aB.x, z1.x) PE(5, aB.y, z1.y) PE(6, aB.z, z1.z) PE(7, aB.w, z1.w)
#undef PE
    gm8[(rowb + r) * 256 + (j0 >> 3) + q] = (unsigned char)bits;
    {
      us8 pk;
#pragma unroll
      for (int m = 0; m < 8; ++m) pk[m] = f2bf(e[m]);
      *(us8*)&att_s[p][r][q * 8] = pk;
    }
#pragma unroll
    for (int v = 0; v < 4; ++v)
      *(uint4*)&wh_s[w][v * 4 + lg][ln * 8] = wreg[v];

    lgkm_barrier();   // publish att_s[p] (+own wh_s); prefetches stay in flight
#pragma unroll
    for (int ks = 0; ks < 4; ++ks) {
      union { us8 u; bf16x8 v; } ac, bc;
      ac.u = *(const us8*)&att_s[p][ln][ks * 32 + lg * 8];
      bc.u = *(const us8*)&wh_s[w][ln][ks * 32 + lg * 8];
      acc = __builtin_amdgcn_mfma_f32_16x16x32_bf16(ac.v, bc.v, acc, 0, 0, 0);
    }
    aA = nA; aB = nB; p ^= 1;
  }

  // row sum: 16 consecutive lanes per row
#pragma unroll
  for (int o = 1; o < 16; o <<= 1) sum += __shfl_xor(sum, o);
  if (q == 0) lrow[rowb + r] = sum;

  // Y write. C/D layout: col(N=f)=lane&15, row(M)=4*(lane>>4)+reg
#pragma unroll
  for (int qq = 0; qq < 4; ++qq)
    yws[(rowb + lg * 4 + qq) * 64 + w * 16 + ln] = acc[qq];
}

// ---------------- k2: PURE att store stream (no MFMA, no loop barriers) ----------------
// 8-row strips, 2048 blocks, tiny LDS -> high occupancy. Per thread: fixed row
// slot + j-column; per iter: 1 L2 zv load, mask nibble, 4 exp, 1 nt f32x4 store.
__global__ __launch_bounds__(256)
void k2_att(const unsigned char* __restrict__ gm8, const float* __restrict__ s1g,
            const float* __restrict__ s2g, const float* __restrict__ lrow,
            float* __restrict__ att)
{
  __shared__ unsigned char bm_s[8][256];   // 2 KB
  __shared__ float s1_s[8], il_s[8];

  const int t = threadIdx.x;
  const int b = blockIdx.y;
  const int r0 = blockIdx.x * 8;
  const size_t rowb = (size_t)(b * 2048 + r0);

  {  // stage masks: 8 rows x 256 B
    const int rr = t >> 5, off = (t & 31) * 8;
    *(uint2*)&bm_s[rr][off] =
        *(const uint2*)&gm8[(rowb + rr) * 256 + off];
  }
  if (t < 8) {
    float L = lrow[rowb + t];
    s1_s[t] = s1g[rowb + t];
    il_s[t] = (L > 0.f) ? 1.f / L : -1.f;
  }
  __syncthreads();

  const int rslot = t >> 5;            // row 0..7
  const int jpos = (t & 31) << 2;
  const float s1r = s1_s[rslot];
  const float il  = il_s[rslot];
  const bool uni  = (il < 0.f);
  const float* __restrict__ z = s2g + b * 2048;
  float* __restrict__ arow = att + (rowb + rslot) * 2048;

  for (int j0 = 0; j0 < 2048; j0 += 128) {
    const int j = j0 + jpos;
    const float4 zv = *(const float4*)&z[j];
    const unsigned byte = bm_s[rslot][j >> 3];
    const int sh = j & 7;              // 0 or 4
    f32x4 o;
#define PW(dst, zz, k)                                              \
    { float e = __expf(lrelu(s1r + (zz))) * il;                     \
      dst = uni ? INV_N : (((byte >> (sh + (k))) & 1u) ? e : 0.f); }
    PW(o[0], zv.x, 0) PW(o[1], zv.y, 1) PW(o[2], zv.z, 2) PW(o[3], zv.w, 3)
#undef PW
    __builtin_nontemporal_store(o, (f32x4*)&arow[j]);
  }
}

// ---------------- k3: hout = elu(Y * il); sentinel rows (never) use uniform mean ----
__global__ __launch_bounds__(256)
void k3_elu(const float* __restrict__ yws, const float* __restrict__ lrow,
            const unsigned short* __restrict__ WhT, float* __restrict__ hout)
{
  const size_t idx = ((size_t)blockIdx.x * 256 + threadIdx.x) * 4;
  const int row = (int)(idx >> 6);          // global row in [0, 8*2048)
  const int f0  = (int)(idx & 63);
  const float L = lrow[row];
  float4 o;
  if (L > 0.f) {
    const float il = 1.f / L;
    float4 y = *(const float4*)&yws[idx];
    float x;
    x = y.x * il; o.x = (x > 0.f) ? x : expm1f(x);
    x = y.y * il; o.y = (x > 0.f) ? x : expm1f(x);
    x = y.z * il; o.z = (x > 0.f) ? x : expm1f(x);
    x = y.w * il; o.w = (x > 0.f) ? x : expm1f(x);
  } else {
    // no-neighbor row: uniform attention -> mean of Wh columns (never taken here)
    const int bb = row >> 11;
    float s[4] = {0.f, 0.f, 0.f, 0.f};
    for (int j = 0; j < 2048; ++j)
#pragma unroll
      for (int k = 0; k < 4; ++k) {
        unsigned short u = WhT[((size_t)(bb * 64 + f0 + k)) * 2048 + j];
        union { unsigned v; float f; } c; c.v = (unsigned)u << 16;
        s[k] += c.f;
      }
#pragma unroll
    for (int k = 0; k < 4; ++k) {
      float x = s[k] * INV_N;
      ((float*)&o)[k] = (x > 0.f) ? x : expm1f(x);
    }
  }
  *(float4*)&hout[idx] = o;
}

extern "C" void kernel_launch(void* const* d_in, const int* in_sizes, int n_in,
                              void* d_out, int out_size, void* d_ws, size_t ws_size,
                              hipStream_t stream)
{
  const float* h   = (const float*)d_in[0];
  const int*   adj = (const int*)d_in[1];
  const float* W   = (const float*)d_in[2];
  const float* a   = (const float*)d_in[3];
  float* hout = (float*)d_out;
  float* att  = hout + (size_t)8 * 2048 * 64;

  char* ws = (char*)d_ws;
  unsigned short* WhT = (unsigned short*)ws;                        // 2 MB
  float* s1 = (float*)(ws + (size_t)(2u << 20));                    // 64 KB each
  float* s2 = s1 + 16384;
  float* lr = s2 + 16384;
  unsigned char* gm8 = (unsigned char*)(ws + (size_t)(2u << 20) + 3 * 65536); // 4 MB
  float* yws = (float*)(ws + (size_t)(2u << 20) + 3 * 65536 + (4u << 20));    // 4 MB

  k0_wh <<<dim3(32, 8),   256, 0, stream>>>(h, W, a, WhT, s1, s2);
  k1y   <<<dim3(128, 8),  256, 0, stream>>>(adj, WhT, s1, s2, lr, gm8, yws);
  k2_att<<<dim3(256, 8),  256, 0, stream>>>(gm8, s1, s2, lr, att);
  k3_elu<<<dim3(1024),    256, 0, stream>>>(yws, lr, WhT, hout);
}